// Round 8
// baseline (174.702 us; speedup 1.0000x reference)
//
#include <hip/hip_runtime.h>
#include <hip/hip_bf16.h>
#include <math.h>

// Problem constants
#define BATCH 256
#define CIN 3
#define HW 128
#define OC 16
#define POOLED 63          // pooled spatial dim
#define FEAT 63504         // OC*63*63
#define NH 256
#define FANIN 512
#define NO 10
#define CHW (CIN*HW*HW)    // 49152

#define SSTRIDE 133        // LDS row stride (odd, ==5 mod 32 -> <=2-way read conflicts)

// ---------------- Kernel 1: conv3x3 + bias + relu + maxpool2x2, fused transpose --
// Block = (pooled row i, 8-batch tile); staging fully coalesced (R7: FETCH 48MB ok).
// R7 post-mortem: VGPR=72 < acc[64]+V[16] -> allocator rematerialized an LDS
// read PER FMA OPERAND (~1728 extra ds_reads/item, 2.4x VALU bloat, 4-way bank
// conflicts on the even-bank stride-130 layout). Fixes:
//  (1) V pinned via asm "+v" -- value is "modified" by the asm, so reloading
//      from LDS is illegal; remat path dead.
//  (2) oc split into TWO sequential 8-oc passes (#pragma unroll 1): pressure =
//      32 acc + 16 V + addr ~= 65 VGPR, inside the allocator's comfort tier,
//      so it has no reason to fight. Cost: +48 ds_reads/item (~3%).
//  (3) stride 130 -> 133 (odd): compute-read banks <=2-way (free).
__global__ __launch_bounds__(256) void conv_pool_kernel(const float* __restrict__ inp,
                                                        const float* __restrict__ cw,
                                                        const float* __restrict__ cb,
                                                        float* __restrict__ featsT) {
    __shared__ float sV[96 * SSTRIDE];        // [ (c*4+dy)*8 + b_l ][SSTRIDE] = 51,072 B
    const int t  = threadIdx.x;
    const int i  = blockIdx.x;      // 0..62 pooled row
    const int b0 = blockIdx.y * 8;  // batch tile base
    const int y0 = 2 * i;           // input rows y0..y0+3

    // ---- stage: 3072 float4 total, 12 per thread, coalesced along x ----
#pragma unroll
    for (int it = 0; it < 12; ++it) {
        const int q  = t + 256 * it;     // 0..3071
        const int r  = q >> 5;           // row id 0..95
        const int x4 = q & 31;           // float4 index within row
        const int b_l = r / 12;
        const int rem = r % 12;
        const int c   = rem >> 2;
        const int dy  = rem & 3;
        const float4 v = *(const float4*)
            &inp[((size_t)(b0 + b_l) * CIN + c) * (HW * HW) + (y0 + dy) * HW + 4 * x4];
        const int base = ((c * 4 + dy) * 8 + b_l) * SSTRIDE + 4 * x4;
        sV[base + 0] = v.x;
        sV[base + 1] = v.y;
        sV[base + 2] = v.z;
        sV[base + 3] = v.w;
    }
    __syncthreads();

    // ---- compute: items m = t and t+256; item -> j = m>>3, b_l = m&7 ----
    for (int m = t; m < 504; m += 256) {
        const int j   = m >> 3;          // 0..62
        const int b_l = m & 7;
        const int x0  = 2 * j;

#pragma unroll 1
        for (int p = 0; p < 2; ++p) {    // two 8-oc passes, NOT unrolled
            const int ocb = p * 8;

            float acc[8][2][2];
#pragma unroll
            for (int o = 0; o < 8; ++o) {
                acc[o][0][0] = 0.f; acc[o][0][1] = 0.f;
                acc[o][1][0] = 0.f; acc[o][1][1] = 0.f;
            }

#pragma unroll
            for (int c = 0; c < CIN; ++c) {
                float V[4][4];
#pragma unroll
                for (int dy = 0; dy < 4; ++dy)
#pragma unroll
                    for (int dx = 0; dx < 4; ++dx)
                        V[dy][dx] = sV[((c * 4 + dy) * 8 + b_l) * SSTRIDE + x0 + dx];

                // Pin each V element in a VGPR: the asm "modifies" the value,
                // so re-deriving it by another LDS read is illegal -> no remat.
#pragma unroll
                for (int dy = 0; dy < 4; ++dy)
#pragma unroll
                    for (int dx = 0; dx < 4; ++dx)
                        asm volatile("" : "+v"(V[dy][dx]));

#pragma unroll
                for (int ky = 0; ky < 3; ++ky)
#pragma unroll
                    for (int kx = 0; kx < 3; ++kx)
#pragma unroll
                        for (int o = 0; o < 8; ++o) {
                            const float w = cw[(((ocb + o) * CIN + c) * 3 + ky) * 3 + kx];
                            acc[o][0][0] += w * V[ky    ][kx    ];
                            acc[o][0][1] += w * V[ky    ][kx + 1];
                            acc[o][1][0] += w * V[ky + 1][kx    ];
                            acc[o][1][1] += w * V[ky + 1][kx + 1];
                        }
            }

#pragma unroll
            for (int o = 0; o < 8; ++o) {
                const float mx = fmaxf(fmaxf(acc[o][0][0], acc[o][0][1]),
                                       fmaxf(acc[o][1][0], acc[o][1][1]));
                const float rr = fmaxf(mx + cb[ocb + o], 0.0f);
                featsT[(size_t)((ocb + o) * 3969 + i * POOLED + j) * BATCH + b0 + b_l] = rr;
            }
        }
    }
}

// ---------------- Kernel 2: sparse hidden layer, float4 gather -------------------
// R7 accounting: hidden ~80-90us, the largest kernel. Old version: per (h,k) the
// row was read by 4 separate b-waves as 256B loads (4x the load instrs + 4x the
// address math). New: block = one h, 512 threads = 8 k-streams x 64 lanes; ONE
// wave reads the whole 1KB featsT row as dwordx4 (16B/lane sweet spot); each
// lane owns 4 consecutive b. LDS reduce across the 8 streams.
__global__ __launch_bounds__(512) void hidden_kernel(const float* __restrict__ featsT,
                                                     const int* __restrict__ hidx,
                                                     const float* __restrict__ hw,
                                                     const float* __restrict__ hb,
                                                     float* __restrict__ hiddenT) {
    __shared__ int   sidx[FANIN];
    __shared__ float swt[FANIN];
    __shared__ float red[8][256];
    const int h  = blockIdx.x;
    const int t  = threadIdx.x;
    sidx[t] = hidx[h * FANIN + t];
    swt[t]  = hw[h * FANIN + t];
    __syncthreads();

    const int lane = t & 63;
    const int ws   = t >> 6;        // 0..7 k-stream (= wave)
    float ax = 0.f, ay = 0.f, az = 0.f, aw = 0.f;
#pragma unroll 16
    for (int kk = 0; kk < 64; ++kk) {
        const int k = ws * 64 + kk;
        const float4 v = *(const float4*)&featsT[(size_t)sidx[k] * BATCH + 4 * lane];
        const float  w = swt[k];
        ax += v.x * w; ay += v.y * w; az += v.z * w; aw += v.w * w;
    }
    red[ws][4 * lane + 0] = ax;
    red[ws][4 * lane + 1] = ay;
    red[ws][4 * lane + 2] = az;
    red[ws][4 * lane + 3] = aw;
    __syncthreads();

    if (t < 256) {
        float s = hb[h];
#pragma unroll
        for (int w8 = 0; w8 < 8; ++w8) s += red[w8][t];
        hiddenT[h * BATCH + t] = 1.0f / (1.0f + __expf(-s));
    }
}

// ---------------- Kernel 3: dense 256->10 output layer ---------------------------
// grid (10 o, 16 b-tiles) = 160 blocks; 256 threads = 16 b x 16 h-groups;
// each thread sums 16 h, LDS tree-reduce across groups. (unchanged)
__global__ __launch_bounds__(256) void out_kernel(const float* __restrict__ hiddenT,
                                                  const float* __restrict__ ow,
                                                  const float* __restrict__ ob,
                                                  float* __restrict__ out) {
    __shared__ float red[256];
    const int o  = blockIdx.x;          // 0..9
    const int bt = blockIdx.y;          // 0..15
    const int tb = threadIdx.x & 15;    // b within tile
    const int hg = threadIdx.x >> 4;    // 0..15 h-group
    const int b  = bt * 16 + tb;
    float acc = 0.f;
#pragma unroll
    for (int k = 0; k < 16; ++k) {
        const int h = hg * 16 + k;
        acc += hiddenT[h * BATCH + b] * ow[o * NH + h];
    }
    red[threadIdx.x] = acc;
    __syncthreads();
    if (hg == 0) {
        float s = 0.f;
#pragma unroll
        for (int g = 0; g < 16; ++g) s += red[g * 16 + tb];
        out[b * NO + o] = 1.0f / (1.0f + __expf(-(s + ob[o])));
    }
}

extern "C" void kernel_launch(void* const* d_in, const int* in_sizes, int n_in,
                              void* d_out, int out_size, void* d_ws, size_t ws_size,
                              hipStream_t stream) {
    const float* inputs   = (const float*)d_in[0];
    const float* conv_w   = (const float*)d_in[1];
    const float* conv_b   = (const float*)d_in[2];
    const int*   hidden_i = (const int*)d_in[3];
    const float* hidden_w = (const float*)d_in[4];
    const float* hidden_b = (const float*)d_in[5];
    const float* out_w    = (const float*)d_in[6];
    const float* out_b    = (const float*)d_in[7];
    float* out = (float*)d_out;

    char* ws = (char*)d_ws;
    float* featsT  = (float*)ws;                                    // 65,028,096 B
    float* hiddenT = (float*)(ws + (size_t)FEAT * BATCH * 4);       //    262,144 B

    conv_pool_kernel<<<dim3(63, 32), 256, 0, stream>>>(inputs, conv_w, conv_b, featsT);
    hidden_kernel<<<NH, 512, 0, stream>>>(featsT, hidden_i, hidden_w, hidden_b, hiddenT);
    out_kernel<<<dim3(NO, 16), 256, 0, stream>>>(hiddenT, out_w, out_b, out);
}

// Round 9
// 173.714 us; speedup vs baseline: 1.0057x; 1.0057x over previous
//
#include <hip/hip_runtime.h>
#include <hip/hip_fp16.h>
#include <math.h>

// Problem constants
#define BATCH 256
#define CIN 3
#define HW 128
#define OC 16
#define POOLED 63          // pooled spatial dim
#define FEAT 63504         // OC*63*63
#define NH 256
#define FANIN 512
#define NO 10
#define CHW (CIN*HW*HW)    // 49152

#define SS 129             // LDS row stride (odd -> bank spread on reads, float2 staging 2-way free)

// ---------------- Kernel 1: conv3x3 + bias + relu + maxpool2x2, fused transpose --
// Block = (pooled row i, 4-batch tile). Staging: 48 rows x 128 floats as float2,
// ONE full input row per wave-load (64 lanes x 8B = 512B) -- coalesced global,
// 2-way LDS write aliasing (free). LDS 24,768B -> ~6 blocks/CU by LDS (R8 was
// 51KB/3). Compute: 1 item/thread (t<252), two 8-oc passes (R8 structure kept).
// featsT written as FP16: halves conv WRITE and, critically, halves the hidden
// gather traffic (the structure-invariant ~90us: 131MB random-row reads).
__global__ __launch_bounds__(256) void conv_pool_kernel(const float* __restrict__ inp,
                                                        const float* __restrict__ cw,
                                                        const float* __restrict__ cb,
                                                        __half* __restrict__ featsT) {
    __shared__ float sV[48 * SS];             // [b_l*12 + c*4 + dy][SS] = 24,768 B
    const int t  = threadIdx.x;
    const int i  = blockIdx.x;      // 0..62 pooled row
    const int b0 = blockIdx.y * 4;  // batch tile base (0..63 tiles)
    const int y0 = 2 * i;           // input rows y0..y0+3

    // ---- stage: 48 rows x 64 float2 = 3072 float2, 12 per thread ----
#pragma unroll
    for (int it = 0; it < 12; ++it) {
        const int q   = t + 256 * it;    // 0..3071
        const int r   = q >> 6;          // row id 0..47
        const int ln  = q & 63;          // float2 index within row
        const int b_l = r / 12;
        const int rem = r % 12;
        const int c   = rem >> 2;
        const int dy  = rem & 3;
        const float2 v = *(const float2*)
            &inp[((size_t)(b0 + b_l) * CIN + c) * (HW * HW) + (y0 + dy) * HW + 2 * ln];
        const int base = r * SS + 2 * ln;
        sV[base + 0] = v.x;
        sV[base + 1] = v.y;
    }
    __syncthreads();

    // ---- compute: 1 item/thread: j = t>>2 (0..62), b_l = t&3 ----
    if (t < 252) {
        const int j   = t >> 2;
        const int b_l = t & 3;
        const int x0  = 2 * j;

#pragma unroll 1
        for (int p = 0; p < 2; ++p) {    // two 8-oc passes, NOT unrolled
            const int ocb = p * 8;

            float acc[8][2][2];
#pragma unroll
            for (int o = 0; o < 8; ++o) {
                acc[o][0][0] = 0.f; acc[o][0][1] = 0.f;
                acc[o][1][0] = 0.f; acc[o][1][1] = 0.f;
            }

#pragma unroll
            for (int c = 0; c < CIN; ++c) {
                float V[4][4];
#pragma unroll
                for (int dy = 0; dy < 4; ++dy)
#pragma unroll
                    for (int dx = 0; dx < 4; ++dx)
                        V[dy][dx] = sV[(b_l * 12 + c * 4 + dy) * SS + x0 + dx];

                // Pin each V element in a VGPR (no remat through the asm).
#pragma unroll
                for (int dy = 0; dy < 4; ++dy)
#pragma unroll
                    for (int dx = 0; dx < 4; ++dx)
                        asm volatile("" : "+v"(V[dy][dx]));

#pragma unroll
                for (int ky = 0; ky < 3; ++ky)
#pragma unroll
                    for (int kx = 0; kx < 3; ++kx)
#pragma unroll
                        for (int o = 0; o < 8; ++o) {
                            const float w = cw[(((ocb + o) * CIN + c) * 3 + ky) * 3 + kx];
                            acc[o][0][0] += w * V[ky    ][kx    ];
                            acc[o][0][1] += w * V[ky    ][kx + 1];
                            acc[o][1][0] += w * V[ky + 1][kx    ];
                            acc[o][1][1] += w * V[ky + 1][kx + 1];
                        }
            }

#pragma unroll
            for (int o = 0; o < 8; ++o) {
                const float mx = fmaxf(fmaxf(acc[o][0][0], acc[o][0][1]),
                                       fmaxf(acc[o][1][0], acc[o][1][1]));
                const float rr = fmaxf(mx + cb[ocb + o], 0.0f);
                featsT[(size_t)((ocb + o) * 3969 + i * POOLED + j) * BATCH + b0 + b_l] =
                    __float2half_rn(rr);
            }
        }
    }
}

// ---------------- Kernel 2: sparse hidden layer, fp16 gather ---------------------
// Block = one h, 512 threads = 8 k-streams x 64 lanes. Row is now 512B (fp16):
// one wave-load (64 lanes x 8B ushort-quad) covers the WHOLE row -- half the
// traffic of R8. Each lane owns 4 consecutive b. LDS reduce across 8 streams.
__global__ __launch_bounds__(512) void hidden_kernel(const __half* __restrict__ featsT,
                                                     const int* __restrict__ hidx,
                                                     const float* __restrict__ hw,
                                                     const float* __restrict__ hb,
                                                     float* __restrict__ hiddenT) {
    __shared__ int   sidx[FANIN];
    __shared__ float swt[FANIN];
    __shared__ float red[8][256];
    const int h  = blockIdx.x;
    const int t  = threadIdx.x;
    sidx[t] = hidx[h * FANIN + t];
    swt[t]  = hw[h * FANIN + t];
    __syncthreads();

    const int lane = t & 63;
    const int ws   = t >> 6;        // 0..7 k-stream (= wave)
    float a0 = 0.f, a1 = 0.f, a2 = 0.f, a3 = 0.f;
#pragma unroll 16
    for (int kk = 0; kk < 64; ++kk) {
        const int k = ws * 64 + kk;
        const __half2* rp =
            reinterpret_cast<const __half2*>(featsT + (size_t)sidx[k] * BATCH) + 2 * lane;
        const __half2 p0 = rp[0];
        const __half2 p1 = rp[1];
        const float2 f0 = __half22float2(p0);
        const float2 f1 = __half22float2(p1);
        const float  w  = swt[k];
        a0 += f0.x * w; a1 += f0.y * w; a2 += f1.x * w; a3 += f1.y * w;
    }
    red[ws][4 * lane + 0] = a0;
    red[ws][4 * lane + 1] = a1;
    red[ws][4 * lane + 2] = a2;
    red[ws][4 * lane + 3] = a3;
    __syncthreads();

    if (t < 256) {
        float s = hb[h];
#pragma unroll
        for (int w8 = 0; w8 < 8; ++w8) s += red[w8][t];
        hiddenT[h * BATCH + t] = 1.0f / (1.0f + __expf(-s));
    }
}

// ---------------- Kernel 3: dense 256->10 output layer ---------------------------
// grid (10 o, 16 b-tiles) = 160 blocks; 256 threads = 16 b x 16 h-groups;
// each thread sums 16 h, LDS tree-reduce across groups. (unchanged)
__global__ __launch_bounds__(256) void out_kernel(const float* __restrict__ hiddenT,
                                                  const float* __restrict__ ow,
                                                  const float* __restrict__ ob,
                                                  float* __restrict__ out) {
    __shared__ float red[256];
    const int o  = blockIdx.x;          // 0..9
    const int bt = blockIdx.y;          // 0..15
    const int tb = threadIdx.x & 15;    // b within tile
    const int hg = threadIdx.x >> 4;    // 0..15 h-group
    const int b  = bt * 16 + tb;
    float acc = 0.f;
#pragma unroll
    for (int k = 0; k < 16; ++k) {
        const int h = hg * 16 + k;
        acc += hiddenT[h * BATCH + b] * ow[o * NH + h];
    }
    red[threadIdx.x] = acc;
    __syncthreads();
    if (hg == 0) {
        float s = 0.f;
#pragma unroll
        for (int g = 0; g < 16; ++g) s += red[g * 16 + tb];
        out[b * NO + o] = 1.0f / (1.0f + __expf(-(s + ob[o])));
    }
}

extern "C" void kernel_launch(void* const* d_in, const int* in_sizes, int n_in,
                              void* d_out, int out_size, void* d_ws, size_t ws_size,
                              hipStream_t stream) {
    const float* inputs   = (const float*)d_in[0];
    const float* conv_w   = (const float*)d_in[1];
    const float* conv_b   = (const float*)d_in[2];
    const int*   hidden_i = (const int*)d_in[3];
    const float* hidden_w = (const float*)d_in[4];
    const float* hidden_b = (const float*)d_in[5];
    const float* out_w    = (const float*)d_in[6];
    const float* out_b    = (const float*)d_in[7];
    float* out = (float*)d_out;

    char* ws = (char*)d_ws;
    __half* featsT  = (__half*)ws;                                  // 32,514,048 B
    float*  hiddenT = (float*)(ws + (size_t)FEAT * BATCH * 2);      //    262,144 B

    conv_pool_kernel<<<dim3(63, 64), 256, 0, stream>>>(inputs, conv_w, conv_b, featsT);
    hidden_kernel<<<NH, 512, 0, stream>>>(featsT, hidden_i, hidden_w, hidden_b, hiddenT);
    out_kernel<<<dim3(NO, 16), 256, 0, stream>>>(hiddenT, out_w, out_b, out);
}

// Round 10
// 164.242 us; speedup vs baseline: 1.0637x; 1.0577x over previous
//
#include <hip/hip_runtime.h>
#include <hip/hip_fp16.h>
#include <math.h>

// Problem constants
#define BATCH 256
#define CIN 3
#define HW 128
#define OC 16
#define POOLED 63          // pooled spatial dim
#define FEAT 63504         // OC*63*63
#define NH 256
#define FANIN 512
#define NO 10
#define CHW (CIN*HW*HW)    // 49152

#define SS 129             // LDS row stride (odd)

// ---------------- Kernel 1: conv3x3 + bias + relu + maxpool2x2, fused transpose --
// R9 post-mortems applied:
//  (1) __launch_bounds__(256, 1): explicitly allow 1 wave/EU so the register
//      allocator's budget opens to 512 VGPRs. Six formulations pinned at
//      VGPR<=68 with load-remat VALU bloat; this is the one untried knob.
//  (2) WRITE amplification fix: fp16 x 4-batch tiles = 8B per (oc,j) write;
//      the 8 blocks sharing each 64B featsT line previously landed on 8
//      different XCDs -> 4x partial-sector writeback (WRITE 128.7MB vs 32.5
//      logical). New 1-D grid bijection: id -> u=id&7 (XCD via round-robin
//      dispatch), v=id>>3, b-tile tt = u*8 + (v&7), i = v>>3. All tiles of a
//      64B line (tt in [8u,8u+8)) run on XCD u -> its L2 merges the partials.
__global__ __launch_bounds__(256, 1) void conv_pool_kernel(const float* __restrict__ inp,
                                                           const float* __restrict__ cw,
                                                           const float* __restrict__ cb,
                                                           __half* __restrict__ featsT) {
    __shared__ float sV[48 * SS];             // [b_l*12 + c*4 + dy][SS] = 24,768 B
    const int t  = threadIdx.x;
    const int id = blockIdx.x;               // 0..4031
    const int u  = id & 7;                   // XCD slot
    const int v  = id >> 3;                  // 0..503
    const int tt = u * 8 + (v & 7);          // b-tile 0..63
    const int i  = v >> 3;                   // pooled row 0..62
    const int b0 = tt * 4;                   // batch tile base
    const int y0 = 2 * i;                    // input rows y0..y0+3

    // ---- stage: 48 rows x 64 float2 = 3072 float2, 12 per thread ----
#pragma unroll
    for (int it = 0; it < 12; ++it) {
        const int q   = t + 256 * it;    // 0..3071
        const int r   = q >> 6;          // row id 0..47
        const int ln  = q & 63;          // float2 index within row
        const int b_l = r / 12;
        const int rem = r % 12;
        const int c   = rem >> 2;
        const int dy  = rem & 3;
        const float2 vv = *(const float2*)
            &inp[((size_t)(b0 + b_l) * CIN + c) * (HW * HW) + (y0 + dy) * HW + 2 * ln];
        const int base = r * SS + 2 * ln;
        sV[base + 0] = vv.x;
        sV[base + 1] = vv.y;
    }
    __syncthreads();

    // ---- compute: 1 item/thread: j = t>>2 (0..62), b_l = t&3 ----
    if (t < 252) {
        const int j   = t >> 2;
        const int b_l = t & 3;
        const int x0  = 2 * j;

#pragma unroll 1
        for (int p = 0; p < 2; ++p) {    // two 8-oc passes, NOT unrolled
            const int ocb = p * 8;

            float acc[8][2][2];
#pragma unroll
            for (int o = 0; o < 8; ++o) {
                acc[o][0][0] = 0.f; acc[o][0][1] = 0.f;
                acc[o][1][0] = 0.f; acc[o][1][1] = 0.f;
            }

#pragma unroll
            for (int c = 0; c < CIN; ++c) {
                float V[4][4];
#pragma unroll
                for (int dy = 0; dy < 4; ++dy)
#pragma unroll
                    for (int dx = 0; dx < 4; ++dx)
                        V[dy][dx] = sV[(b_l * 12 + c * 4 + dy) * SS + x0 + dx];

                // Pin each V element in a VGPR (no remat through the asm).
#pragma unroll
                for (int dy = 0; dy < 4; ++dy)
#pragma unroll
                    for (int dx = 0; dx < 4; ++dx)
                        asm volatile("" : "+v"(V[dy][dx]));

#pragma unroll
                for (int ky = 0; ky < 3; ++ky)
#pragma unroll
                    for (int kx = 0; kx < 3; ++kx)
#pragma unroll
                        for (int o = 0; o < 8; ++o) {
                            const float w = cw[(((ocb + o) * CIN + c) * 3 + ky) * 3 + kx];
                            acc[o][0][0] += w * V[ky    ][kx    ];
                            acc[o][0][1] += w * V[ky    ][kx + 1];
                            acc[o][1][0] += w * V[ky + 1][kx    ];
                            acc[o][1][1] += w * V[ky + 1][kx + 1];
                        }
            }

#pragma unroll
            for (int o = 0; o < 8; ++o) {
                const float mx = fmaxf(fmaxf(acc[o][0][0], acc[o][0][1]),
                                       fmaxf(acc[o][1][0], acc[o][1][1]));
                const float rr = fmaxf(mx + cb[ocb + o], 0.0f);
                featsT[(size_t)((ocb + o) * 3969 + i * POOLED + j) * BATCH + b0 + b_l] =
                    __float2half_rn(rr);
            }
        }
    }
}

// ---------------- Kernel 2: sparse hidden layer, k-split partials ----------------
// R9 falsified the BW theory (fp16 halved traffic, time unchanged) -> latency/
// parallelism-bound. 4x the blocks: grid (256 h, 4 k-quarters) = 1024 blocks,
// 256 threads = 4 waves x 64 lanes; wave w covers k in [q*128+w*32, +32).
// Partials written to hiddenP[q][h][b]; bias+sigmoid moved to out_kernel.
__global__ __launch_bounds__(256) void hidden_kernel(const __half* __restrict__ featsT,
                                                     const int* __restrict__ hidx,
                                                     const float* __restrict__ hw,
                                                     float* __restrict__ hiddenP) {
    __shared__ int   sidx[128];
    __shared__ float swt[128];
    __shared__ float red[4][256];
    const int h = blockIdx.x;
    const int q = blockIdx.y;
    const int t = threadIdx.x;
    if (t < 128) {
        sidx[t] = hidx[h * FANIN + q * 128 + t];
        swt[t]  = hw[h * FANIN + q * 128 + t];
    }
    __syncthreads();

    const int lane = t & 63;
    const int w    = t >> 6;        // 0..3
    float a0 = 0.f, a1 = 0.f, a2 = 0.f, a3 = 0.f;
#pragma unroll 16
    for (int kk = 0; kk < 32; ++kk) {
        const int k = w * 32 + kk;
        const __half2* rp =
            reinterpret_cast<const __half2*>(featsT + (size_t)sidx[k] * BATCH) + 2 * lane;
        const __half2 p0 = rp[0];
        const __half2 p1 = rp[1];
        const float2 f0 = __half22float2(p0);
        const float2 f1 = __half22float2(p1);
        const float  wt = swt[k];
        a0 += f0.x * wt; a1 += f0.y * wt; a2 += f1.x * wt; a3 += f1.y * wt;
    }
    red[w][4 * lane + 0] = a0;
    red[w][4 * lane + 1] = a1;
    red[w][4 * lane + 2] = a2;
    red[w][4 * lane + 3] = a3;
    __syncthreads();

    if (t < 256) {
        const float s = red[0][t] + red[1][t] + red[2][t] + red[3][t];
        hiddenP[((size_t)q * NH + h) * BATCH + t] = s;
    }
}

// ---------------- Kernel 3: partial-sum + bias + sigmoid + dense 256->10 --------
// grid (10 o, 16 b-tiles); 256 threads = 16 b x 16 h-groups. Reads 4 partials
// per (h,b) (1MB, L2-resident), applies sigmoid, dots with ow, LDS reduce.
__global__ __launch_bounds__(256) void out_kernel(const float* __restrict__ hiddenP,
                                                  const float* __restrict__ hb,
                                                  const float* __restrict__ ow,
                                                  const float* __restrict__ ob,
                                                  float* __restrict__ out) {
    __shared__ float red[256];
    const int o  = blockIdx.x;          // 0..9
    const int bt = blockIdx.y;          // 0..15
    const int tb = threadIdx.x & 15;    // b within tile
    const int hg = threadIdx.x >> 4;    // 0..15 h-group
    const int b  = bt * 16 + tb;
    float acc = 0.f;
#pragma unroll
    for (int k = 0; k < 16; ++k) {
        const int h = hg * 16 + k;
        const float s = hiddenP[(0 * NH + h) * BATCH + b]
                      + hiddenP[(1 * NH + h) * BATCH + b]
                      + hiddenP[(2 * NH + h) * BATCH + b]
                      + hiddenP[(3 * NH + h) * BATCH + b] + hb[h];
        const float hs = 1.0f / (1.0f + __expf(-s));
        acc += hs * ow[o * NH + h];
    }
    red[threadIdx.x] = acc;
    __syncthreads();
    if (hg == 0) {
        float s = 0.f;
#pragma unroll
        for (int g = 0; g < 16; ++g) s += red[g * 16 + tb];
        out[b * NO + o] = 1.0f / (1.0f + __expf(-(s + ob[o])));
    }
}

extern "C" void kernel_launch(void* const* d_in, const int* in_sizes, int n_in,
                              void* d_out, int out_size, void* d_ws, size_t ws_size,
                              hipStream_t stream) {
    const float* inputs   = (const float*)d_in[0];
    const float* conv_w   = (const float*)d_in[1];
    const float* conv_b   = (const float*)d_in[2];
    const int*   hidden_i = (const int*)d_in[3];
    const float* hidden_w = (const float*)d_in[4];
    const float* hidden_b = (const float*)d_in[5];
    const float* out_w    = (const float*)d_in[6];
    const float* out_b    = (const float*)d_in[7];
    float* out = (float*)d_out;

    char* ws = (char*)d_ws;
    __half* featsT  = (__half*)ws;                                  // 32,514,048 B
    float*  hiddenP = (float*)(ws + (size_t)FEAT * BATCH * 2);      //  1,048,576 B

    conv_pool_kernel<<<4032, 256, 0, stream>>>(inputs, conv_w, conv_b, featsT);
    hidden_kernel<<<dim3(NH, 4), 256, 0, stream>>>(featsT, hidden_i, hidden_w, hiddenP);
    out_kernel<<<dim3(NO, 16), 256, 0, stream>>>(hiddenP, hidden_b, out_w, out_b, out);
}

// Round 11
// 138.977 us; speedup vs baseline: 1.2571x; 1.1818x over previous
//
#include <hip/hip_runtime.h>
#include <hip/hip_fp16.h>
#include <math.h>

// Problem constants
#define BATCH 256
#define CIN 3
#define HW 128
#define OC 16
#define POOLED 63
#define FEAT 63504         // OC*63*63
#define NH 256
#define FANIN 512
#define NO 10
#define CHW (CIN*HW*HW)    // 49152

#define PADX 134           // LDS x-stride in halves: b-stride 268B -> bank 3b%32, all-distinct
#define ROWS 15            // cdy rows: 12 real (c0..2 x dy0..3) + 3 zero rows (c=3, k>=27 pad)

typedef _Float16 h4 __attribute__((ext_vector_type(4)));
typedef float    f4 __attribute__((ext_vector_type(4)));

// ---------------- Kernel 1: conv3x3+bias+relu+maxpool via MFMA (f16 in, f32 acc) --
// R0-R10: scalar fp32 conv pinned at ~69us = 2.4x the 157TF vector-ALU floor; the
// allocator remats loads in every formulation. This IS a GEMM (M=16 oc, K=27,
// N=126*126*256) -> matrix cores. v_mfma_f32_16x16x16f16, two K=16 MFMAs per
// pre-pool pixel (K 27->32, pad k>=27 reads a zeroed LDS region, A pad = 0).
// Layouts (classic CDNA, C/D m89-verified): A[row=l&15][k=4q+j], B[k][col=l&15],
// D[row=4q+reg][col=l&15], q=l>>4.
// Block = (pooled row i, batch group g of 16); 4 waves split 63 pooled cols.
// LDS sB[cdy15][b16][PADX134] halves = 64,320B: staging writes bank-sequential,
// gather reads spread by 3b%32. XCD write-pairing kept from R10 (g-pairs 2u,2u+1
// share the 64B featsT line and the XCD).
__global__ __launch_bounds__(256) void conv_pool_kernel(const float* __restrict__ inp,
                                                        const float* __restrict__ cw,
                                                        const float* __restrict__ cb,
                                                        __half* __restrict__ featsT) {
    __shared__ _Float16 sB[ROWS * 16 * PADX];     // 64,320 B
    const int t    = threadIdx.x;
    const int l    = t & 63;
    const int w    = t >> 6;        // wave 0..3
    const int q    = l >> 4;        // quarter 0..3
    const int bcol = l & 15;        // A-row / B-col / D-col lane index

    // block decode: id = (2i + (g&1))*8 + (g>>1)  -> g-pairs (2u,2u+1) on one XCD
    const int id = blockIdx.x;
    const int u  = id & 7;
    const int v  = id >> 3;          // 0..125
    const int i  = v >> 1;           // pooled row 0..62
    const int g  = 2 * u + (v & 1);  // batch group 0..15
    const int y0 = 2 * i;

    // ---- zero the k>=27 pad region (rows 192..239 of 16-b-major rows) ----
    {
        unsigned int* z = (unsigned int*)&sB[192 * PADX];   // 192 = 12*16 b-rows
        const int nd = (ROWS * 16 - 192) * PADX / 2;        // 48*134/2 = 3216 dwords
        for (int zz = t; zz < nd; zz += 256) z[zz] = 0u;
    }

    // ---- stage: rows (b_l, c, dy) -> sB[(c*4+dy)*16 + b_l][x], f32->f16 ----
#pragma unroll
    for (int bb = 0; bb < 4; ++bb) {
        const int b_l = w * 4 + bb;
#pragma unroll
        for (int rr = 0; rr < 12; ++rr) {
            const int c  = rr >> 2;
            const int dy = rr & 3;
            const float2 vv = *(const float2*)
                &inp[((size_t)(g * 16 + b_l) * CIN + c) * (HW * HW) + (y0 + dy) * HW + 2 * l];
            *(__half2*)&sB[(size_t)((c * 4 + dy) * 16 + b_l) * PADX + 2 * l] =
                __float22half2_rn(vv);
        }
    }
    __syncthreads();

    // ---- A fragments (weights), bias, per-lane LDS base offsets ----
    h4 aLo, aHi;
    int P[8];
    float bias[4];
#pragma unroll
    for (int m = 0; m < 8; ++m) {
        const int k  = (m < 4) ? (4 * q + m) : (16 + 4 * q + (m - 4));
        // decode k -> (c, ky, kx); c=3 for k>=27 (zero rows)
        const int c  = (k * 57) >> 9;
        const int r2 = k - 9 * c;
        const int ky = (r2 * 11) >> 5;
        const int kx = r2 - 3 * ky;
        P[m] = ((c * 4 + ky) * 16 + bcol) * PADX + kx;
        const float wv = (k < 27) ? cw[bcol * 27 + k] : 0.0f;
        if (m < 4) aLo[m] = (_Float16)wv; else aHi[m - 4] = (_Float16)wv;
    }
#pragma unroll
    for (int r = 0; r < 4; ++r) bias[r] = cb[4 * q + r];

    // ---- pooled-col loop: wave w owns j in [16w, min(16w+16,63)) ----
    const int jend = (16 * w + 16 < 63) ? (16 * w + 16) : 63;
    for (int j = 16 * w; j < jend; ++j) {
        f4 d[2][2];
#pragma unroll
        for (int ys = 0; ys < 2; ++ys)
#pragma unroll
            for (int xs = 0; xs < 2; ++xs) {
                const int U = ys * (16 * PADX) + 2 * j + xs;   // wave-uniform
                h4 bLo, bHi;
#pragma unroll
                for (int jj = 0; jj < 4; ++jj) {
                    bLo[jj] = sB[P[jj]     + U];
                    bHi[jj] = sB[P[4 + jj] + U];
                }
                f4 acc = {0.f, 0.f, 0.f, 0.f};
                acc = __builtin_amdgcn_mfma_f32_16x16x16f16(aLo, bLo, acc, 0, 0, 0);
                acc = __builtin_amdgcn_mfma_f32_16x16x16f16(aHi, bHi, acc, 0, 0, 0);
                d[ys][xs] = acc;
            }
        // maxpool over the 2x2 pixels, bias, relu, store fp16
#pragma unroll
        for (int r = 0; r < 4; ++r) {
            const float m0 = fmaxf(d[0][0][r], d[0][1][r]);
            const float m1 = fmaxf(d[1][0][r], d[1][1][r]);
            const float mv = fmaxf(m0, m1);
            const float rv = fmaxf(mv + bias[r], 0.0f);
            const int oc = 4 * q + r;
            featsT[(size_t)(oc * 3969 + i * POOLED + j) * BATCH + g * 16 + bcol] =
                __float2half_rn(rv);
        }
    }
}

// ---------------- Kernel 2: sparse hidden layer, k-split partials (FROZEN R10) ---
__global__ __launch_bounds__(256) void hidden_kernel(const __half* __restrict__ featsT,
                                                     const int* __restrict__ hidx,
                                                     const float* __restrict__ hw,
                                                     float* __restrict__ hiddenP) {
    __shared__ int   sidx[128];
    __shared__ float swt[128];
    __shared__ float red[4][256];
    const int h = blockIdx.x;
    const int q = blockIdx.y;
    const int t = threadIdx.x;
    if (t < 128) {
        sidx[t] = hidx[h * FANIN + q * 128 + t];
        swt[t]  = hw[h * FANIN + q * 128 + t];
    }
    __syncthreads();

    const int lane = t & 63;
    const int w    = t >> 6;
    float a0 = 0.f, a1 = 0.f, a2 = 0.f, a3 = 0.f;
#pragma unroll 16
    for (int kk = 0; kk < 32; ++kk) {
        const int k = w * 32 + kk;
        const __half2* rp =
            reinterpret_cast<const __half2*>(featsT + (size_t)sidx[k] * BATCH) + 2 * lane;
        const __half2 p0 = rp[0];
        const __half2 p1 = rp[1];
        const float2 f0 = __half22float2(p0);
        const float2 f1 = __half22float2(p1);
        const float  wt = swt[k];
        a0 += f0.x * wt; a1 += f0.y * wt; a2 += f1.x * wt; a3 += f1.y * wt;
    }
    red[w][4 * lane + 0] = a0;
    red[w][4 * lane + 1] = a1;
    red[w][4 * lane + 2] = a2;
    red[w][4 * lane + 3] = a3;
    __syncthreads();

    if (t < 256) {
        const float s = red[0][t] + red[1][t] + red[2][t] + red[3][t];
        hiddenP[((size_t)q * NH + h) * BATCH + t] = s;
    }
}

// ---------------- Kernel 3: partial-sum + sigmoid + dense 256->10 (FROZEN R10) ---
__global__ __launch_bounds__(256) void out_kernel(const float* __restrict__ hiddenP,
                                                  const float* __restrict__ hb,
                                                  const float* __restrict__ ow,
                                                  const float* __restrict__ ob,
                                                  float* __restrict__ out) {
    __shared__ float red[256];
    const int o  = blockIdx.x;
    const int bt = blockIdx.y;
    const int tb = threadIdx.x & 15;
    const int hg = threadIdx.x >> 4;
    const int b  = bt * 16 + tb;
    float acc = 0.f;
#pragma unroll
    for (int k = 0; k < 16; ++k) {
        const int h = hg * 16 + k;
        const float s = hiddenP[(0 * NH + h) * BATCH + b]
                      + hiddenP[(1 * NH + h) * BATCH + b]
                      + hiddenP[(2 * NH + h) * BATCH + b]
                      + hiddenP[(3 * NH + h) * BATCH + b] + hb[h];
        const float hs = 1.0f / (1.0f + __expf(-s));
        acc += hs * ow[o * NH + h];
    }
    red[threadIdx.x] = acc;
    __syncthreads();
    if (hg == 0) {
        float s = 0.f;
#pragma unroll
        for (int gg = 0; gg < 16; ++gg) s += red[gg * 16 + tb];
        out[b * NO + o] = 1.0f / (1.0f + __expf(-(s + ob[o])));
    }
}

extern "C" void kernel_launch(void* const* d_in, const int* in_sizes, int n_in,
                              void* d_out, int out_size, void* d_ws, size_t ws_size,
                              hipStream_t stream) {
    const float* inputs   = (const float*)d_in[0];
    const float* conv_w   = (const float*)d_in[1];
    const float* conv_b   = (const float*)d_in[2];
    const int*   hidden_i = (const int*)d_in[3];
    const float* hidden_w = (const float*)d_in[4];
    const float* hidden_b = (const float*)d_in[5];
    const float* out_w    = (const float*)d_in[6];
    const float* out_b    = (const float*)d_in[7];
    float* out = (float*)d_out;

    char* ws = (char*)d_ws;
    __half* featsT  = (__half*)ws;                                  // 32,514,048 B
    float*  hiddenP = (float*)(ws + (size_t)FEAT * BATCH * 2);      //  1,048,576 B

    conv_pool_kernel<<<1008, 256, 0, stream>>>(inputs, conv_w, conv_b, featsT);
    hidden_kernel<<<dim3(NH, 4), 256, 0, stream>>>(featsT, hidden_i, hidden_w, hiddenP);
    out_kernel<<<dim3(NO, 16), 256, 0, stream>>>(hiddenP, hidden_b, out_w, out_b, out);
}

// Round 12
// 134.992 us; speedup vs baseline: 1.2942x; 1.0295x over previous
//
#include <hip/hip_runtime.h>
#include <hip/hip_fp16.h>
#include <math.h>

// Problem constants
#define BATCH 256
#define CIN 3
#define HW 128
#define OC 16
#define POOLED 63
#define FEAT 63504         // OC*63*63
#define NH 256
#define FANIN 512
#define NO 10

#define PADX 134           // LDS x-stride in halves (even, 67 mod 32 = 3 -> banks spread)
#define ROWS 12            // (c,dy) rows; no zero-pad region needed anymore

typedef _Float16 h4 __attribute__((ext_vector_type(4)));
typedef _Float16 h2v __attribute__((ext_vector_type(2)));
typedef float    f4 __attribute__((ext_vector_type(4)));

// ---------------- Kernel 1: conv3x3+bias+relu+maxpool via MFMA, k-permuted -------
// R11 was LDS-issue-bound: 32 scalar ds_read_u16 vs 8 MFMA per j. MFMA tolerates
// ANY k-permutation if A and B agree. New mapping: quarter q of MFMA s handles
// conv-row rIdx=s*4+q -> (c=rIdx/3, ky=rIdx%3) for rIdx<9, zero-weight otherwise.
// A lane's 4 k-slots jj are then kx=jj at consecutive LDS x -> ONE 8B (2x b32,
// 4-aligned) load per fragment. xs handled in A: xs=0 -> [w0,w1,w2,0], xs=1 ->
// [0,w0,w1,w2]; so ONE B fragment serves BOTH pool columns. Per j: 12 MFMA +
// 6 8B-loads (was 8 MFMA + 32 u16). Zero-slots read row ys (A=0 kills product)
// -> zero-pad region deleted, LDS 51,456B, 3 blocks/CU.
// Layout convention (R11-verified, passed): A[row=l&15][k=4q+jj],
// B[k][col=l&15], D[row=4q+reg][col=l&15].
__global__ __launch_bounds__(256) void conv_pool_kernel(const float* __restrict__ inp,
                                                        const float* __restrict__ cw,
                                                        const float* __restrict__ cb,
                                                        __half* __restrict__ featsT) {
    __shared__ _Float16 sB[ROWS * 16 * PADX];     // 51,456 B
    const int t    = threadIdx.x;
    const int l    = t & 63;
    const int w    = t >> 6;        // wave 0..3
    const int q    = l >> 4;        // quarter 0..3
    const int bcol = l & 15;        // oc for A/D, batch-col for B

    // block decode: g-pairs (2u,2u+1) share featsT 64B lines AND the XCD (R10 fix)
    const int id = blockIdx.x;
    const int u  = id & 7;
    const int v  = id >> 3;          // 0..125
    const int i  = v >> 1;           // pooled row 0..62
    const int g  = 2 * u + (v & 1);  // batch group 0..15
    const int y0 = 2 * i;

    // ---- stage: rows (c,dy) x 16 b -> f16, coalesced float2 per lane ----
#pragma unroll
    for (int bb = 0; bb < 4; ++bb) {
        const int b_l = w * 4 + bb;
#pragma unroll
        for (int rr = 0; rr < 12; ++rr) {
            const int c  = rr >> 2;
            const int dy = rr & 3;
            const float2 vv = *(const float2*)
                &inp[((size_t)(g * 16 + b_l) * CIN + c) * (HW * HW) + (y0 + dy) * HW + 2 * l];
            *(__half2*)&sB[(size_t)((c * 4 + dy) * 16 + b_l) * PADX + 2 * l] =
                __float22half2_rn(vv);
        }
    }
    __syncthreads();

    // ---- per-lane A fragments and B base offsets ----
    h4  aF[3][2];                   // [s][xs]
    int bOff[3][2];                 // [s][ys] LDS half-offsets (sans 2j)
    float bias[4];
#pragma unroll
    for (int s = 0; s < 3; ++s) {
        const int rIdx = s * 4 + q;            // 0..11
        const int c    = (rIdx * 11) >> 5;     // /3 for 0..11
        const int ky   = rIdx - 3 * c;
        const bool valid = (c < 3);
        float wv[3];
#pragma unroll
        for (int kx = 0; kx < 3; ++kx)
            wv[kx] = valid ? cw[(bcol * CIN + c) * 9 + ky * 3 + kx] : 0.0f;
        aF[s][0][0] = (_Float16)wv[0]; aF[s][0][1] = (_Float16)wv[1];
        aF[s][0][2] = (_Float16)wv[2]; aF[s][0][3] = (_Float16)0.0f;
        aF[s][1][0] = (_Float16)0.0f;  aF[s][1][1] = (_Float16)wv[0];
        aF[s][1][2] = (_Float16)wv[1]; aF[s][1][3] = (_Float16)wv[2];
#pragma unroll
        for (int ys = 0; ys < 2; ++ys) {
            const int row = valid ? (c * 4 + ys + ky) : ys;   // any valid row ok when A=0
            bOff[s][ys] = (row * 16 + bcol) * PADX;
        }
    }
#pragma unroll
    for (int r = 0; r < 4; ++r) bias[r] = cb[4 * q + r];

    // ---- pooled-col loop: wave w owns j in [16w, min(16w+16,63)) ----
    const int jend = (16 * w + 16 < 63) ? (16 * w + 16) : 63;
    for (int j = 16 * w; j < jend; ++j) {
        f4 d00 = {0.f,0.f,0.f,0.f}, d01 = d00, d10 = d00, d11 = d00;
#pragma unroll
        for (int s = 0; s < 3; ++s) {
            // B fragment for ys=0 and ys=1: 4 halves at x=2j (4B-aligned)
            const _Float16* p0 = &sB[bOff[s][0] + 2 * j];
            const _Float16* p1 = &sB[bOff[s][1] + 2 * j];
            const h2v a0 = *(const h2v*)p0, a1 = *(const h2v*)(p0 + 2);
            const h2v c0 = *(const h2v*)p1, c1 = *(const h2v*)(p1 + 2);
            const h4 bF0 = {a0[0], a0[1], a1[0], a1[1]};
            const h4 bF1 = {c0[0], c0[1], c1[0], c1[1]};
            d00 = __builtin_amdgcn_mfma_f32_16x16x16f16(aF[s][0], bF0, d00, 0, 0, 0);
            d01 = __builtin_amdgcn_mfma_f32_16x16x16f16(aF[s][1], bF0, d01, 0, 0, 0);
            d10 = __builtin_amdgcn_mfma_f32_16x16x16f16(aF[s][0], bF1, d10, 0, 0, 0);
            d11 = __builtin_amdgcn_mfma_f32_16x16x16f16(aF[s][1], bF1, d11, 0, 0, 0);
        }
        // maxpool 2x2, bias, relu, fp16 store
#pragma unroll
        for (int r = 0; r < 4; ++r) {
            const float mv = fmaxf(fmaxf(d00[r], d01[r]), fmaxf(d10[r], d11[r]));
            const float rv = fmaxf(mv + bias[r], 0.0f);
            const int oc = 4 * q + r;
            featsT[(size_t)(oc * 3969 + i * POOLED + j) * BATCH + g * 16 + bcol] =
                __float2half_rn(rv);
        }
    }
}

// ---------------- Kernel 2: sparse hidden layer, 16B gather ----------------------
// R9 (bytes) and R10 (blocks) both null -> issue/latency-bound. Halve the gather
// instruction count: 16B dwordx4 per lane, half-wave per 512B row, two k-rows
// per wave-load, shfl_xor(32) merges even/odd-k partials.
__global__ __launch_bounds__(256) void hidden_kernel(const __half* __restrict__ featsT,
                                                     const int* __restrict__ hidx,
                                                     const float* __restrict__ hw,
                                                     float* __restrict__ hiddenP) {
    __shared__ int   sidx[128];
    __shared__ float swt[128];
    __shared__ float red[4][256];
    const int h = blockIdx.x;
    const int q = blockIdx.y;
    const int t = threadIdx.x;
    if (t < 128) {
        sidx[t] = hidx[h * FANIN + q * 128 + t];
        swt[t]  = hw[h * FANIN + q * 128 + t];
    }
    __syncthreads();

    const int l   = t & 63;
    const int w   = t >> 6;          // 0..3
    const int hl  = l & 31;          // half-wave lane: b-octet index
    const int sel = l >> 5;          // 0: even k, 1: odd k
    float acc[8] = {0.f,0.f,0.f,0.f,0.f,0.f,0.f,0.f};
#pragma unroll
    for (int m = 0; m < 16; ++m) {
        const int kloc = w * 32 + 2 * m + sel;
        const uint4 v = *(const uint4*)(featsT + (size_t)sidx[kloc] * BATCH + 8 * hl);
        const __half2* hp = reinterpret_cast<const __half2*>(&v);
        const float wt = swt[kloc];
#pragma unroll
        for (int d2 = 0; d2 < 4; ++d2) {
            const float2 f = __half22float2(hp[d2]);
            acc[2 * d2 + 0] += f.x * wt;
            acc[2 * d2 + 1] += f.y * wt;
        }
    }
#pragma unroll
    for (int e = 0; e < 8; ++e) acc[e] += __shfl_xor(acc[e], 32);
    if (sel == 0) {
#pragma unroll
        for (int e = 0; e < 8; ++e) red[w][8 * hl + e] = acc[e];
    }
    __syncthreads();

    if (t < 256) {
        const float s = red[0][t] + red[1][t] + red[2][t] + red[3][t];
        hiddenP[((size_t)q * NH + h) * BATCH + t] = s;
    }
}

// ---------------- Kernel 3: partial-sum + sigmoid + dense 256->10 (FROZEN) ------
__global__ __launch_bounds__(256) void out_kernel(const float* __restrict__ hiddenP,
                                                  const float* __restrict__ hb,
                                                  const float* __restrict__ ow,
                                                  const float* __restrict__ ob,
                                                  float* __restrict__ out) {
    __shared__ float red[256];
    const int o  = blockIdx.x;
    const int bt = blockIdx.y;
    const int tb = threadIdx.x & 15;
    const int hg = threadIdx.x >> 4;
    const int b  = bt * 16 + tb;
    float acc = 0.f;
#pragma unroll
    for (int k = 0; k < 16; ++k) {
        const int h = hg * 16 + k;
        const float s = hiddenP[(0 * NH + h) * BATCH + b]
                      + hiddenP[(1 * NH + h) * BATCH + b]
                      + hiddenP[(2 * NH + h) * BATCH + b]
                      + hiddenP[(3 * NH + h) * BATCH + b] + hb[h];
        const float hs = 1.0f / (1.0f + __expf(-s));
        acc += hs * ow[o * NH + h];
    }
    red[threadIdx.x] = acc;
    __syncthreads();
    if (hg == 0) {
        float s = 0.f;
#pragma unroll
        for (int gg = 0; gg < 16; ++gg) s += red[gg * 16 + tb];
        out[b * NO + o] = 1.0f / (1.0f + __expf(-(s + ob[o])));
    }
}

extern "C" void kernel_launch(void* const* d_in, const int* in_sizes, int n_in,
                              void* d_out, int out_size, void* d_ws, size_t ws_size,
                              hipStream_t stream) {
    const float* inputs   = (const float*)d_in[0];
    const float* conv_w   = (const float*)d_in[1];
    const float* conv_b   = (const float*)d_in[2];
    const int*   hidden_i = (const int*)d_in[3];
    const float* hidden_w = (const float*)d_in[4];
    const float* hidden_b = (const float*)d_in[5];
    const float* out_w    = (const float*)d_in[6];
    const float* out_b    = (const float*)d_in[7];
    float* out = (float*)d_out;

    char* ws = (char*)d_ws;
    __half* featsT  = (__half*)ws;                                  // 32,514,048 B
    float*  hiddenP = (float*)(ws + (size_t)FEAT * BATCH * 2);      //  1,048,576 B

    conv_pool_kernel<<<1008, 256, 0, stream>>>(inputs, conv_w, conv_b, featsT);
    hidden_kernel<<<dim3(NH, 4), 256, 0, stream>>>(featsT, hidden_i, hidden_w, hiddenP);
    out_kernel<<<dim3(NO, 16), 256, 0, stream>>>(hiddenP, hidden_b, out_w, out_b, out);
}